// Round 10
// baseline (278.194 us; speedup 1.0000x reference)
//
#include <hip/hip_runtime.h>
#include <hip/hip_bf16.h>
#include <stdint.h>

typedef __bf16 bf16x4 __attribute__((ext_vector_type(4)));
typedef __bf16 bf16x8 __attribute__((ext_vector_type(8)));
typedef float  f32x4  __attribute__((ext_vector_type(4)));

#define LOG2E 1.44269504088896f

__device__ __forceinline__ void gl2lds16(const __bf16* g, __bf16* l) {
    __builtin_amdgcn_global_load_lds(
        (const __attribute__((address_space(1))) void*)g,
        (__attribute__((address_space(3))) void*)l, 16, 0, 0);
}

// ---------------- fused fp32 -> bf16 for all three tensors (one launch) ----------------------
__global__ __launch_bounds__(256) void cvt3_f32_bf16(
    const float* __restrict__ x,  __bf16* __restrict__ xb,
    const float* __restrict__ wq, __bf16* __restrict__ wqb,
    const float* __restrict__ wp, __bf16* __restrict__ wpb) {
    const int bid = blockIdx.x;
    const float* in; __bf16* out; int base;
    if (bid < 4096)      { in = x;  out = xb;  base = bid; }
    else if (bid < 5632) { in = wq; out = wqb; base = bid - 4096; }
    else                 { in = wp; out = wpb; base = bid - 5632; }
    size_t i = ((size_t)base * 256 + threadIdx.x) * 8;
    float4 a = ((const float4*)(in + i))[0];
    float4 b = ((const float4*)(in + i))[1];
    bf16x8 v;
    v[0] = (__bf16)a.x; v[1] = (__bf16)a.y; v[2] = (__bf16)a.z; v[3] = (__bf16)a.w;
    v[4] = (__bf16)b.x; v[5] = (__bf16)b.y; v[6] = (__bf16)b.z; v[7] = (__bf16)b.w;
    *(bf16x8*)(out + i) = v;
}

// ---------------- 128x256 8-phase GEMM: exact-round grids, swizzled, counted vmcnt -----------
// r9's proven skeleton at BM=128/BN=256 so grids land on exact occupancy rounds:
//   qkv (12,64)=768 blocks = 3 exact rounds @ 1 block/CU;  proj (4,64)=256 = 1 exact round.
//   (r9's 256^2 had 384 blocks = 1.5 rounds -> ran as 2, ~25-33% idle tail.)
// 8 waves, wave owns 64x64 (wm=wave>>2, wn=wave&3), acc[4][4]; LDS 96KB (As 32K + Bs 64K).
// Phases (ks,mh): ph1(0,0) ph2(0,1) ph3(1,0) ph4(1,1); bf[4] loaded at ph1/ph3, af[2]/phase,
// 8 MFMA per phase. Swizzle identical to r9 (read row = base+lr, verified conflict-free):
//   read col  = lq*8 ^ ((lr&7)<<3)  (ks1: ^32);  stage src col = ((l&7)^(l>>3))<<3.
// Staging (48 chunks/K-tile): every wave 2 B(t+1)@ph1 + 2 B(t+1)@ph2 into nxt; A-chunk groups:
//   waves 0,1,4,5 own mh0-region A rows -> stage A(t+2)@ph4 into CUR (mh0's last read = ph3);
//   waves 2,3,6,7 own mh1-region A rows -> stage A(t+1)@ph3 into nxt.
// Gate end-of-iter: mh0-group vmcnt(2) (its 2 A(t+2) stay in flight), mh1-group vmcnt(0);
// t=T-2: all vmcnt(0); t=T-1: no gate. Prologue mirrors r9.
template<typename TC>
__global__ __launch_bounds__(512, 2) void gemm_8ph2(
    const __bf16* __restrict__ A, const __bf16* __restrict__ B,
    const float* __restrict__ bias, TC* __restrict__ C,
    int M, int N, int K, int lda, int ldb, int ldc)
{
    __shared__ __bf16 As[2][128][64];   // 32 KB
    __shared__ __bf16 Bs[2][256][64];   // 64 KB

    const int tid = threadIdx.x;
    const int wave = tid >> 6, l = tid & 63;
    const int lr = l & 15, lq = l >> 4;
    const int wm = wave >> 2, wn = wave & 3;
    const int m0 = blockIdx.y * 128, n0 = blockIdx.x * 256;

    const int cswz  = (lq * 8) ^ ((lr & 7) << 3);
    const int cswz1 = cswz ^ 32;

    const int srow  = l >> 3;
    const int selem = (((l & 7) ^ (l >> 3)) << 3);

    // A chunks (2/wave): group g0 = waves 0,1,4,5 cover mh0 rows; g1 = 2,3,6,7 cover mh1.
    const int g1 = (wave >> 1) & 1;
    const int abase = (wave >> 2) * 64 + g1 * 32 + (wave & 1) * 16;
    const int rA0 = abase, rA1 = abase + 8;
    // B chunks (4/wave): rows wave*32 + {0,8,16,24}
    const int rB0 = wave * 32;

    const __bf16* gA0 = A + (size_t)(m0 + rA0 + srow) * lda + selem;
    const __bf16* gA1 = A + (size_t)(m0 + rA1 + srow) * lda + selem;
    const __bf16* gB0 = B + (size_t)(n0 + rB0 +  0 + srow) * ldb + selem;
    const __bf16* gB1 = B + (size_t)(n0 + rB0 +  8 + srow) * ldb + selem;
    const __bf16* gB2 = B + (size_t)(n0 + rB0 + 16 + srow) * ldb + selem;
    const __bf16* gB3 = B + (size_t)(n0 + rB0 + 24 + srow) * ldb + selem;

    const int T = K >> 6;
    f32x4 acc[4][4] = {};

    // prologue: tile0 fully; then g0 waves prefetch their A(t=1) and leave it in flight
    gl2lds16(gA0, &As[0][rA0][0]);
    gl2lds16(gA1, &As[0][rA1][0]);
    gl2lds16(gB0, &Bs[0][rB0 +  0][0]);
    gl2lds16(gB1, &Bs[0][rB0 +  8][0]);
    gl2lds16(gB2, &Bs[0][rB0 + 16][0]);
    gl2lds16(gB3, &Bs[0][rB0 + 24][0]);
    if (T > 1 && !g1) {
        gl2lds16(gA0 + 64, &As[1][rA0][0]);
        gl2lds16(gA1 + 64, &As[1][rA1][0]);
        asm volatile("s_waitcnt vmcnt(2)" ::: "memory");
    } else {
        asm volatile("s_waitcnt vmcnt(0)" ::: "memory");
    }
    __builtin_amdgcn_s_barrier();

    bf16x8 bf[4];
    for (int t = 0; t < T; ++t) {
        const int cur = t & 1, nxt = cur ^ 1;
        const int ko  = (t + 1) << 6;

        // ---- phase 1: ks0, mh0 (loads bf ks0; stages 2 B(t+1)) ----
        {
            bf16x8 af[2];
#pragma unroll
            for (int i = 0; i < 2; ++i)
                af[i] = *(const bf16x8*)&As[cur][wm*64 + i*16 + lr][cswz];
#pragma unroll
            for (int j = 0; j < 4; ++j)
                bf[j] = *(const bf16x8*)&Bs[cur][wn*64 + j*16 + lr][cswz];
            if (t + 1 < T) {
                gl2lds16(gB0 + ko, &Bs[nxt][rB0 + 0][0]);
                gl2lds16(gB1 + ko, &Bs[nxt][rB0 + 8][0]);
            }
            __builtin_amdgcn_s_barrier();
            asm volatile("s_waitcnt lgkmcnt(0)" ::: "memory");
            __builtin_amdgcn_s_setprio(1);
#pragma unroll
            for (int i = 0; i < 2; ++i)
#pragma unroll
                for (int j = 0; j < 4; ++j)
                    acc[i][j] = __builtin_amdgcn_mfma_f32_16x16x32_bf16(bf[j], af[i], acc[i][j], 0, 0, 0);
            __builtin_amdgcn_s_setprio(0);
            __builtin_amdgcn_s_barrier();
        }
        // ---- phase 2: ks0, mh1 (stages 2 B(t+1)) ----
        {
            bf16x8 af[2];
#pragma unroll
            for (int i = 0; i < 2; ++i)
                af[i] = *(const bf16x8*)&As[cur][wm*64 + (2 + i)*16 + lr][cswz];
            if (t + 1 < T) {
                gl2lds16(gB2 + ko, &Bs[nxt][rB0 + 16][0]);
                gl2lds16(gB3 + ko, &Bs[nxt][rB0 + 24][0]);
            }
            __builtin_amdgcn_s_barrier();
            asm volatile("s_waitcnt lgkmcnt(0)" ::: "memory");
            __builtin_amdgcn_s_setprio(1);
#pragma unroll
            for (int i = 0; i < 2; ++i)
#pragma unroll
                for (int j = 0; j < 4; ++j)
                    acc[2 + i][j] = __builtin_amdgcn_mfma_f32_16x16x32_bf16(bf[j], af[i], acc[2 + i][j], 0, 0, 0);
            __builtin_amdgcn_s_setprio(0);
            __builtin_amdgcn_s_barrier();
        }
        // ---- phase 3: ks1, mh0 (loads bf ks1; g1 waves stage their A(t+1)) ----
        {
            bf16x8 af[2];
#pragma unroll
            for (int i = 0; i < 2; ++i)
                af[i] = *(const bf16x8*)&As[cur][wm*64 + i*16 + lr][cswz1];
#pragma unroll
            for (int j = 0; j < 4; ++j)
                bf[j] = *(const bf16x8*)&Bs[cur][wn*64 + j*16 + lr][cswz1];
            if (t + 1 < T && g1) {
                gl2lds16(gA0 + ko, &As[nxt][rA0][0]);
                gl2lds16(gA1 + ko, &As[nxt][rA1][0]);
            }
            __builtin_amdgcn_s_barrier();
            asm volatile("s_waitcnt lgkmcnt(0)" ::: "memory");
            __builtin_amdgcn_s_setprio(1);
#pragma unroll
            for (int i = 0; i < 2; ++i)
#pragma unroll
                for (int j = 0; j < 4; ++j)
                    acc[i][j] = __builtin_amdgcn_mfma_f32_16x16x32_bf16(bf[j], af[i], acc[i][j], 0, 0, 0);
            __builtin_amdgcn_s_setprio(0);
            __builtin_amdgcn_s_barrier();
        }
        // ---- phase 4: ks1, mh1 (g0 waves stage A(t+2) into cur; gate; iter barrier) ----
        {
            bf16x8 af[2];
#pragma unroll
            for (int i = 0; i < 2; ++i)
                af[i] = *(const bf16x8*)&As[cur][wm*64 + (2 + i)*16 + lr][cswz1];
            if (t + 2 < T && !g1) {
                gl2lds16(gA0 + ko + 64, &As[cur][rA0][0]);
                gl2lds16(gA1 + ko + 64, &As[cur][rA1][0]);
            }
            __builtin_amdgcn_s_barrier();
            asm volatile("s_waitcnt lgkmcnt(0)" ::: "memory");
            __builtin_amdgcn_s_setprio(1);
#pragma unroll
            for (int i = 0; i < 2; ++i)
#pragma unroll
                for (int j = 0; j < 4; ++j)
                    acc[2 + i][j] = __builtin_amdgcn_mfma_f32_16x16x32_bf16(bf[j], af[i], acc[2 + i][j], 0, 0, 0);
            __builtin_amdgcn_s_setprio(0);
            if (t + 2 < T) {
                if (!g1) asm volatile("s_waitcnt vmcnt(2)" ::: "memory");
                else     asm volatile("s_waitcnt vmcnt(0)" ::: "memory");
                __builtin_amdgcn_s_barrier();
            } else if (t + 1 < T) {
                asm volatile("s_waitcnt vmcnt(0)" ::: "memory");
                __builtin_amdgcn_s_barrier();
            }
        }
    }

    // epilogue: row = m0 + wm*64 + ii*16 + lr; col = n0 + wn*64 + j*16 + lq*4 (+reg)
    float4 bv4[4] = {{0.f,0.f,0.f,0.f},{0.f,0.f,0.f,0.f},{0.f,0.f,0.f,0.f},{0.f,0.f,0.f,0.f}};
    if (bias)
#pragma unroll
        for (int j = 0; j < 4; ++j)
            bv4[j] = *(const float4*)&bias[n0 + wn*64 + j*16 + lq*4];
#pragma unroll
    for (int ii = 0; ii < 4; ++ii) {
        const int row = m0 + wm*64 + ii*16 + lr;
#pragma unroll
        for (int j = 0; j < 4; ++j) {
            const int col = n0 + wn*64 + j*16 + lq*4;
            if constexpr (sizeof(TC) == 2) {
                bf16x4 ob;
                ob[0] = (__bf16)(acc[ii][j][0] + bv4[j].x);
                ob[1] = (__bf16)(acc[ii][j][1] + bv4[j].y);
                ob[2] = (__bf16)(acc[ii][j][2] + bv4[j].z);
                ob[3] = (__bf16)(acc[ii][j][3] + bv4[j].w);
                *(bf16x4*)&C[(size_t)row * ldc + col] = ob;
            } else {
                float4 ov;
                ov.x = acc[ii][j][0] + bv4[j].x;
                ov.y = acc[ii][j][1] + bv4[j].y;
                ov.z = acc[ii][j][2] + bv4[j].z;
                ov.w = acc[ii][j][3] + bv4[j].w;
                *(float4*)&C[(size_t)row * ldc + col] = ov;
            }
        }
    }
}

// ---------------- fallback GEMM: fp32 ingest, stage16 cvt ------------------------------------
__device__ __forceinline__ void stage16(const float* __restrict__ g, __bf16* l) {
    float4 a = ((const float4*)g)[0];
    float4 b = ((const float4*)g)[1];
    float4 c = ((const float4*)g)[2];
    float4 d = ((const float4*)g)[3];
    bf16x8 lo, hi;
    lo[0] = (__bf16)a.x; lo[1] = (__bf16)a.y; lo[2] = (__bf16)a.z; lo[3] = (__bf16)a.w;
    lo[4] = (__bf16)b.x; lo[5] = (__bf16)b.y; lo[6] = (__bf16)b.z; lo[7] = (__bf16)b.w;
    hi[0] = (__bf16)c.x; hi[1] = (__bf16)c.y; hi[2] = (__bf16)c.z; hi[3] = (__bf16)c.w;
    hi[4] = (__bf16)d.x; hi[5] = (__bf16)d.y; hi[6] = (__bf16)d.z; hi[7] = (__bf16)d.w;
    ((bf16x8*)l)[0] = lo;
    ((bf16x8*)l)[1] = hi;
}
__device__ __forceinline__ void stage16(const __bf16* __restrict__ g, __bf16* l) {
    ((bf16x8*)l)[0] = ((const bf16x8*)g)[0];
    ((bf16x8*)l)[1] = ((const bf16x8*)g)[1];
}

template<typename TA, typename TB, typename TC>
__global__ __launch_bounds__(256) void gemm_bt(
    const TA* __restrict__ A, const TB* __restrict__ B,
    const float* __restrict__ bias, TC* __restrict__ C,
    int M, int N, int K, int lda, int ldb, int ldc)
{
    __shared__ __bf16 As[128][40];
    __shared__ __bf16 Bs[128][40];
    const int tid = threadIdx.x;
    const int wave = tid >> 6, lane = tid & 63;
    const int lr = lane & 15, lq = lane >> 4;
    const int m0 = blockIdx.y * 128, n0 = blockIdx.x * 128;
    const int wm = (wave >> 1) * 64, wn = (wave & 1) * 64;
    const int srow = tid >> 1, scol = (tid & 1) * 16;

    f32x4 acc[4][4] = {};
    const TA* agp = A + (size_t)(m0 + srow) * lda + scol;
    const TB* bgp = B + (size_t)(n0 + srow) * ldb + scol;

    for (int k0 = 0; k0 < K; k0 += 32) {
        __syncthreads();
        stage16(agp + k0, &As[srow][scol]);
        stage16(bgp + k0, &Bs[srow][scol]);
        __syncthreads();
        bf16x8 af[4], bf[4];
        for (int i = 0; i < 4; ++i) af[i] = *(const bf16x8*)&As[wm + i * 16 + lr][lq * 8];
        for (int j = 0; j < 4; ++j) bf[j] = *(const bf16x8*)&Bs[wn + j * 16 + lr][lq * 8];
        for (int i = 0; i < 4; ++i)
            for (int j = 0; j < 4; ++j)
                acc[i][j] = __builtin_amdgcn_mfma_f32_16x16x32_bf16(bf[j], af[i], acc[i][j], 0, 0, 0);
    }

    float4 bv4[4] = {{0.f,0.f,0.f,0.f},{0.f,0.f,0.f,0.f},{0.f,0.f,0.f,0.f},{0.f,0.f,0.f,0.f}};
    if (bias)
        for (int j = 0; j < 4; ++j)
            bv4[j] = *(const float4*)&bias[n0 + wn + j * 16 + lq * 4];
    for (int i = 0; i < 4; ++i) {
        const int row = m0 + wm + i * 16 + lr;
        for (int j = 0; j < 4; ++j) {
            const int col = n0 + wn + j * 16 + lq * 4;
            if constexpr (sizeof(TC) == 2) {
                bf16x4 ob;
                ob[0] = (__bf16)(acc[i][j][0] + bv4[j].x);
                ob[1] = (__bf16)(acc[i][j][1] + bv4[j].y);
                ob[2] = (__bf16)(acc[i][j][2] + bv4[j].z);
                ob[3] = (__bf16)(acc[i][j][3] + bv4[j].w);
                *(bf16x4*)&C[(size_t)row * ldc + col] = ob;
            } else {
                float4 ov;
                ov.x = acc[i][j][0] + bv4[j].x;
                ov.y = acc[i][j][1] + bv4[j].y;
                ov.z = acc[i][j][2] + bv4[j].z;
                ov.w = acc[i][j][3] + bv4[j].w;
                *(float4*)&C[(size_t)row * ldc + col] = ov;
            }
        }
    }
}

// ---------------- flash attention v7: BM=256, 8 waves x 32 Q rows, 4 waves/SIMD --------------
__global__ __launch_bounds__(512, 4) void attn_kernel(__bf16* __restrict__ qkv)
{
    __shared__ __bf16 Ks[2][64][72];   // [buf][j][d], padded
    __shared__ __bf16 Vt[2][64][72];   // [buf][d][j' packed], padded

    const int tid = threadIdx.x;
    const int wave = tid >> 6, lane = tid & 63;
    const int lr = lane & 15, lq = lane >> 4;

    const int bid = blockIdx.x;          // 512 blocks: 64 bh x 8 qt
    const int xcd = bid & 7, slot = bid >> 3;
    const int bh = xcd * 8 + (slot >> 3);
    const int qt = slot & 7;
    const int b = bh >> 4, h = bh & 15;
    const int rowbase = b * 2048;
    const int q0 = qt * 256;
    const float c1 = 0.125f * LOG2E;

    bf16x8 qf[2][2];
    for (int mt = 0; mt < 2; ++mt)
        for (int ks = 0; ks < 2; ++ks) {
            bf16x8 v = *(const bf16x8*)(qkv +
                (size_t)(rowbase + q0 + wave * 32 + mt * 16 + lr) * 3072 + h * 64 + ks * 32 + lq * 8);
            bf16x8 w;
            for (int e = 0; e < 8; ++e) w[e] = (__bf16)((float)v[e] * c1);
            qf[mt][ks] = w;
        }

    bf16x8 ones8;
    for (int e = 0; e < 8; ++e) ones8[e] = (__bf16)1.0f;

    f32x4 l_acc[2] = {};
    f32x4 o_acc[2][4] = {};

    const int tid2 = tid & 255;
    const int kr = tid2 >> 2, kc = (tid2 & 3) * 16;
    const int g0 = tid2 & 15;
    const int vj0 = g0 * 4, vd0 = (tid2 >> 4) * 4;
    const int vcol = ((g0 >> 3) * 32) + ((g0 & 3) * 8) + (((g0 >> 2) & 1) * 4);
    const __bf16* kbase = qkv + (size_t)(rowbase + kr) * 3072 + 1024 + h * 64 + kc;
    const __bf16* vbase = qkv + (size_t)(rowbase + vj0) * 3072 + 2048 + h * 64 + vd0;

    bf16x8 ka, kb;
    uint2 t0, t1, t2, t3;

    if (wave >= 4) {
        ka = ((const bf16x8*)kbase)[0];
        kb = ((const bf16x8*)kbase)[1];
        *(bf16x8*)&Ks[0][kr][kc] = ka;
        *(bf16x8*)(&Ks[0][kr][kc] + 8) = kb;
    } else {
        t0 = *(const uint2*)(vbase);
        t1 = *(const uint2*)(vbase + 3072);
        t2 = *(const uint2*)(vbase + 6144);
        t3 = *(const uint2*)(vbase + 9216);
        uint2 c0 = { (t0.x & 0xffffu) | (t1.x << 16), (t2.x & 0xffffu) | (t3.x << 16) };
        uint2 d1 = { (t0.x >> 16) | (t1.x & 0xffff0000u), (t2.x >> 16) | (t3.x & 0xffff0000u) };
        uint2 c2 = { (t0.y & 0xffffu) | (t1.y << 16), (t2.y & 0xffffu) | (t3.y << 16) };
        uint2 d3 = { (t0.y >> 16) | (t1.y & 0xffff0000u), (t2.y >> 16) | (t3.y & 0xffff0000u) };
        *(uint2*)&Vt[0][vd0 + 0][vcol] = c0;
        *(uint2*)&Vt[0][vd0 + 1][vcol] = d1;
        *(uint2*)&Vt[0][vd0 + 2][vcol] = c2;
        *(uint2*)&Vt[0][vd0 + 3][vcol] = d3;
    }

    for (int it = 0; it < 32; ++it) {
        const int cur = it & 1;
        __syncthreads();

        if (it + 1 < 32) {
            if (wave >= 4) {
                const __bf16* kg = kbase + (size_t)(it + 1) * 64 * 3072;
                ka = ((const bf16x8*)kg)[0];
                kb = ((const bf16x8*)kg)[1];
            } else {
                const __bf16* vg = vbase + (size_t)(it + 1) * 64 * 3072;
                t0 = *(const uint2*)(vg);
                t1 = *(const uint2*)(vg + 3072);
                t2 = *(const uint2*)(vg + 6144);
                t3 = *(const uint2*)(vg + 9216);
            }
        }

        for (int pi = 0; pi < 2; ++pi) {
            f32x4 s[2][2] = {};
            for (int ks = 0; ks < 2; ++ks) {
                bf16x8 kf0 = *(const bf16x8*)&Ks[cur][(2 * pi + 0) * 16 + lr][ks * 32 + lq * 8];
                bf16x8 kf1 = *(const bf16x8*)&Ks[cur][(2 * pi + 1) * 16 + lr][ks * 32 + lq * 8];
                for (int mt = 0; mt < 2; ++mt) {
                    s[mt][0] = __builtin_amdgcn_mfma_f32_16x16x32_bf16(kf0, qf[mt][ks], s[mt][0], 0, 0, 0);
                    s[mt][1] = __builtin_amdgcn_mfma_f32_16x16x32_bf16(kf1, qf[mt][ks], s[mt][1], 0, 0, 0);
                }
            }
            bf16x8 pfrag[2];
            for (int mt = 0; mt < 2; ++mt) {
                for (int t = 0; t < 2; ++t)
                    for (int r = 0; r < 4; ++r) {
                        float p = __builtin_amdgcn_exp2f(s[mt][t][r]);
                        pfrag[mt][t * 4 + r] = (__bf16)p;
                    }
            }
            for (int mt = 0; mt < 2; ++mt)
                l_acc[mt] = __builtin_amdgcn_mfma_f32_16x16x32_bf16(ones8, pfrag[mt], l_acc[mt], 0, 0, 0);
            for (int dt = 0; dt < 4; ++dt) {
                bf16x8 vf = *(const bf16x8*)&Vt[cur][dt * 16 + lr][pi * 32 + lq * 8];
                for (int mt = 0; mt < 2; ++mt)
                    o_acc[mt][dt] = __builtin_amdgcn_mfma_f32_16x16x32_bf16(vf, pfrag[mt], o_acc[mt][dt], 0, 0, 0);
            }
        }

        if (it + 1 < 32) {
            const int nb = cur ^ 1;
            if (wave >= 4) {
                *(bf16x8*)&Ks[nb][kr][kc] = ka;
                *(bf16x8*)(&Ks[nb][kr][kc] + 8) = kb;
            } else {
                uint2 c0 = { (t0.x & 0xffffu) | (t1.x << 16), (t2.x & 0xffffu) | (t3.x << 16) };
                uint2 d1 = { (t0.x >> 16) | (t1.x & 0xffff0000u), (t2.x >> 16) | (t3.x & 0xffff0000u) };
                uint2 c2 = { (t0.y & 0xffffu) | (t1.y << 16), (t2.y & 0xffffu) | (t3.y << 16) };
                uint2 d3 = { (t0.y >> 16) | (t1.y & 0xffff0000u), (t2.y >> 16) | (t3.y & 0xffff0000u) };
                *(uint2*)&Vt[nb][vd0 + 0][vcol] = c0;
                *(uint2*)&Vt[nb][vd0 + 1][vcol] = d1;
                *(uint2*)&Vt[nb][vd0 + 2][vcol] = c2;
                *(uint2*)&Vt[nb][vd0 + 3][vcol] = d3;
            }
        }
    }

    for (int mt = 0; mt < 2; ++mt) {
        float inv = 1.f / l_acc[mt][0];
        for (int dt = 0; dt < 4; ++dt) {
            bf16x4 ob;
            for (int r = 0; r < 4; ++r) ob[r] = (__bf16)(o_acc[mt][dt][r] * inv);
            *(bf16x4*)(qkv + (size_t)(rowbase + q0 + wave * 32 + mt * 16 + lr) * 3072 +
                       h * 64 + dt * 16 + lq * 4) = ob;
        }
    }
}

extern "C" void kernel_launch(void* const* d_in, const int* in_sizes, int n_in,
                              void* d_out, int out_size, void* d_ws, size_t ws_size,
                              hipStream_t stream) {
    const float* x     = (const float*)d_in[0];   // [8192, 1024] fp32
    const float* Wqkv  = (const float*)d_in[1];   // [3072, 1024] fp32
    const float* Wproj = (const float*)d_in[2];   // [1024, 1024] fp32
    const float* bproj = (const float*)d_in[3];   // [1024] fp32
    float* out   = (float*)d_out;                 // [8192, 1024] fp32
    __bf16* qkvb = (__bf16*)d_ws;                 // [8192, 3072] bf16

    const size_t QKV_E = (size_t)8192 * 3072;
    const size_t X_E   = (size_t)8192 * 1024;
    const size_t WQ_E  = (size_t)3072 * 1024;
    const size_t WP_E  = (size_t)1024 * 1024;
    const bool fast = ws_size >= (QKV_E + X_E + WQ_E + WP_E) * sizeof(__bf16);

    if (fast) {
        __bf16* xb  = qkvb + QKV_E;
        __bf16* wqb = xb + X_E;
        __bf16* wpb = wqb + WQ_E;
        cvt3_f32_bf16<<<dim3(6144), 256, 0, stream>>>(x, xb, Wqkv, wqb, Wproj, wpb);
        gemm_8ph2<__bf16><<<dim3(12, 64), 512, 0, stream>>>(
            xb, wqb, nullptr, qkvb, 8192, 3072, 1024, 1024, 1024, 3072);
        attn_kernel<<<dim3(512), 512, 0, stream>>>(qkvb);
        gemm_8ph2<float><<<dim3(4, 64), 512, 0, stream>>>(
            qkvb, wpb, bproj, out, 8192, 1024, 1024, 3072, 1024, 1024);
    } else {
        gemm_bt<float, float, __bf16><<<dim3(24, 64), 256, 0, stream>>>(
            x, Wqkv, nullptr, qkvb, 8192, 3072, 1024, 1024, 1024, 3072);
        attn_kernel<<<dim3(512), 512, 0, stream>>>(qkvb);
        gemm_bt<__bf16, float, float><<<dim3(8, 64), 256, 0, stream>>>(
            qkvb, Wproj, bproj, out, 8192, 1024, 1024, 3072, 1024, 1024);
    }
}

// Round 11
// 263.174 us; speedup vs baseline: 1.0571x; 1.0571x over previous
//
#include <hip/hip_runtime.h>
#include <hip/hip_bf16.h>
#include <stdint.h>

typedef __bf16 bf16x4 __attribute__((ext_vector_type(4)));
typedef __bf16 bf16x8 __attribute__((ext_vector_type(8)));
typedef float  f32x4  __attribute__((ext_vector_type(4)));

#define LOG2E 1.44269504088896f

__device__ __forceinline__ void gl2lds16(const __bf16* g, __bf16* l) {
    __builtin_amdgcn_global_load_lds(
        (const __attribute__((address_space(1))) void*)g,
        (__attribute__((address_space(3))) void*)l, 16, 0, 0);
}

// ---------------- fused fp32 -> bf16 for all three tensors (one launch) ----------------------
__global__ __launch_bounds__(256) void cvt3_f32_bf16(
    const float* __restrict__ x,  __bf16* __restrict__ xb,
    const float* __restrict__ wq, __bf16* __restrict__ wqb,
    const float* __restrict__ wp, __bf16* __restrict__ wpb) {
    const int bid = blockIdx.x;
    const float* in; __bf16* out; int base;
    if (bid < 4096)      { in = x;  out = xb;  base = bid; }
    else if (bid < 5632) { in = wq; out = wqb; base = bid - 4096; }
    else                 { in = wp; out = wpb; base = bid - 5632; }
    size_t i = ((size_t)base * 256 + threadIdx.x) * 8;
    float4 a = ((const float4*)(in + i))[0];
    float4 b = ((const float4*)(in + i))[1];
    bf16x8 v;
    v[0] = (__bf16)a.x; v[1] = (__bf16)a.y; v[2] = (__bf16)a.z; v[3] = (__bf16)a.w;
    v[4] = (__bf16)b.x; v[5] = (__bf16)b.y; v[6] = (__bf16)b.z; v[7] = (__bf16)b.w;
    *(bf16x8*)(out + i) = v;
}

// ---------------- 128x128 m97-structure GEMM, BK=64 + r9-verified swizzle --------------------
// Two proven fixes on the r5 baseline (83.5us qkv, MfmaUtil 26, 6.3M conflict-cycles):
//  (a) BK 32->64: halves __syncthreads barrier-drains per MFMA (2 per 64-K instead of 4).
//      LDS 32KB/block keeps ~5 blocks/CU (unlike the documented BK=128@64KB occupancy cliff).
//  (b) swizzle (r9: measured ZERO conflicts): LDS col-block cb (8 elems) of row r holds global
//      block cb ^ (r&7). gl2lds16 dest is linear (lane*16B), so lane l of an 8-row chunk
//      pre-swizzles its GLOBAL col: selem = ((l&7) ^ (l>>3))*8. Reads fetch global block
//      ks*4+lq at LDS block (ks*4+lq)^(lr&7): cswz = lq*8 ^ ((lr&7)<<3), ks1 = cswz^32.
//      Octets hit 8 distinct 16B slots; 128B rows are bank-neutral -> conflict-free.
// Old layout's octet analysis: row*64B -> lanes lr,lr+2 share banks = ~4-way, ~5cyc/read tax.
// Epilogue: swapped-operand MFMA -> each thread holds 4 consecutive cols -> 16 vector stores.
template<typename TC>
__global__ __launch_bounds__(256) void gemm_bk64(
    const __bf16* __restrict__ A, const __bf16* __restrict__ B,
    const float* __restrict__ bias, TC* __restrict__ C,
    int M, int N, int K, int lda, int ldb, int ldc)
{
    __shared__ __bf16 As[128][64];   // 16 KB
    __shared__ __bf16 Bs[128][64];   // 16 KB
    const int tid = threadIdx.x;
    const int wave = tid >> 6, lane = tid & 63;
    const int lr = lane & 15, lq = lane >> 4;
    const int m0 = blockIdx.y * 128, n0 = blockIdx.x * 128;
    const int wm = (wave >> 1) * 64, wn = (wave & 1) * 64;

    const int cswz  = (lq * 8) ^ ((lr & 7) << 3);
    const int cswz1 = cswz ^ 32;

    const int srow  = lane >> 3;                    // row within 8-row chunk
    const int selem = ((lane & 7) ^ srow) << 3;     // pre-swizzled global col

    f32x4 acc[4][4] = {};

    const __bf16* ag[4]; const __bf16* bg[4];
    int rls[4];
    for (int s = 0; s < 4; ++s) {
        int chunk = wave * 4 + s;                   // 16 chunks x 8 rows = 128
        rls[s] = chunk * 8;
        ag[s] = A + (size_t)(m0 + chunk * 8 + srow) * lda + selem;
        bg[s] = B + (size_t)(n0 + chunk * 8 + srow) * ldb + selem;
    }

    for (int k0 = 0; k0 < K; k0 += 64) {
        __syncthreads();
#pragma unroll
        for (int s = 0; s < 4; ++s) gl2lds16(ag[s] + k0, &As[rls[s]][0]);
#pragma unroll
        for (int s = 0; s < 4; ++s) gl2lds16(bg[s] + k0, &Bs[rls[s]][0]);
        __syncthreads();   // compiler emits vmcnt(0) drain before barrier (gl2lds16 landed)
#pragma unroll
        for (int ks = 0; ks < 2; ++ks) {
            const int cc = ks ? cswz1 : cswz;
            bf16x8 af[4], bf[4];
#pragma unroll
            for (int i = 0; i < 4; ++i) af[i] = *(const bf16x8*)&As[wm + i * 16 + lr][cc];
#pragma unroll
            for (int j = 0; j < 4; ++j) bf[j] = *(const bf16x8*)&Bs[wn + j * 16 + lr][cc];
#pragma unroll
            for (int i = 0; i < 4; ++i)
#pragma unroll
                for (int j = 0; j < 4; ++j)
                    acc[i][j] = __builtin_amdgcn_mfma_f32_16x16x32_bf16(bf[j], af[i], acc[i][j], 0, 0, 0);
        }
    }

    // epilogue: D row axis (lq,reg) = N (4 consecutive cols), D col axis (lr) = M row
    float4 bv4[4] = {{0.f,0.f,0.f,0.f},{0.f,0.f,0.f,0.f},{0.f,0.f,0.f,0.f},{0.f,0.f,0.f,0.f}};
    if (bias)
        for (int j = 0; j < 4; ++j)
            bv4[j] = *(const float4*)&bias[n0 + wn + j * 16 + lq * 4];
    for (int i = 0; i < 4; ++i) {
        const int row = m0 + wm + i * 16 + lr;
        for (int j = 0; j < 4; ++j) {
            const int col = n0 + wn + j * 16 + lq * 4;
            if constexpr (sizeof(TC) == 2) {
                bf16x4 ob;
                ob[0] = (__bf16)(acc[i][j][0] + bv4[j].x);
                ob[1] = (__bf16)(acc[i][j][1] + bv4[j].y);
                ob[2] = (__bf16)(acc[i][j][2] + bv4[j].z);
                ob[3] = (__bf16)(acc[i][j][3] + bv4[j].w);
                *(bf16x4*)&C[(size_t)row * ldc + col] = ob;
            } else {
                float4 ov;
                ov.x = acc[i][j][0] + bv4[j].x;
                ov.y = acc[i][j][1] + bv4[j].y;
                ov.z = acc[i][j][2] + bv4[j].z;
                ov.w = acc[i][j][3] + bv4[j].w;
                *(float4*)&C[(size_t)row * ldc + col] = ov;
            }
        }
    }
}

// ---------------- fallback GEMM: fp32 ingest, stage16 cvt ------------------------------------
__device__ __forceinline__ void stage16(const float* __restrict__ g, __bf16* l) {
    float4 a = ((const float4*)g)[0];
    float4 b = ((const float4*)g)[1];
    float4 c = ((const float4*)g)[2];
    float4 d = ((const float4*)g)[3];
    bf16x8 lo, hi;
    lo[0] = (__bf16)a.x; lo[1] = (__bf16)a.y; lo[2] = (__bf16)a.z; lo[3] = (__bf16)a.w;
    lo[4] = (__bf16)b.x; lo[5] = (__bf16)b.y; lo[6] = (__bf16)b.z; lo[7] = (__bf16)b.w;
    hi[0] = (__bf16)c.x; hi[1] = (__bf16)c.y; hi[2] = (__bf16)c.z; hi[3] = (__bf16)c.w;
    hi[4] = (__bf16)d.x; hi[5] = (__bf16)d.y; hi[6] = (__bf16)d.z; hi[7] = (__bf16)d.w;
    ((bf16x8*)l)[0] = lo;
    ((bf16x8*)l)[1] = hi;
}
__device__ __forceinline__ void stage16(const __bf16* __restrict__ g, __bf16* l) {
    ((bf16x8*)l)[0] = ((const bf16x8*)g)[0];
    ((bf16x8*)l)[1] = ((const bf16x8*)g)[1];
}

template<typename TA, typename TB, typename TC>
__global__ __launch_bounds__(256) void gemm_bt(
    const TA* __restrict__ A, const TB* __restrict__ B,
    const float* __restrict__ bias, TC* __restrict__ C,
    int M, int N, int K, int lda, int ldb, int ldc)
{
    __shared__ __bf16 As[128][40];
    __shared__ __bf16 Bs[128][40];
    const int tid = threadIdx.x;
    const int wave = tid >> 6, lane = tid & 63;
    const int lr = lane & 15, lq = lane >> 4;
    const int m0 = blockIdx.y * 128, n0 = blockIdx.x * 128;
    const int wm = (wave >> 1) * 64, wn = (wave & 1) * 64;
    const int srow = tid >> 1, scol = (tid & 1) * 16;

    f32x4 acc[4][4] = {};
    const TA* agp = A + (size_t)(m0 + srow) * lda + scol;
    const TB* bgp = B + (size_t)(n0 + srow) * ldb + scol;

    for (int k0 = 0; k0 < K; k0 += 32) {
        __syncthreads();
        stage16(agp + k0, &As[srow][scol]);
        stage16(bgp + k0, &Bs[srow][scol]);
        __syncthreads();
        bf16x8 af[4], bf[4];
        for (int i = 0; i < 4; ++i) af[i] = *(const bf16x8*)&As[wm + i * 16 + lr][lq * 8];
        for (int j = 0; j < 4; ++j) bf[j] = *(const bf16x8*)&Bs[wn + j * 16 + lr][lq * 8];
        for (int i = 0; i < 4; ++i)
            for (int j = 0; j < 4; ++j)
                acc[i][j] = __builtin_amdgcn_mfma_f32_16x16x32_bf16(bf[j], af[i], acc[i][j], 0, 0, 0);
    }

    float4 bv4[4] = {{0.f,0.f,0.f,0.f},{0.f,0.f,0.f,0.f},{0.f,0.f,0.f,0.f},{0.f,0.f,0.f,0.f}};
    if (bias)
        for (int j = 0; j < 4; ++j)
            bv4[j] = *(const float4*)&bias[n0 + wn + j * 16 + lq * 4];
    for (int i = 0; i < 4; ++i) {
        const int row = m0 + wm + i * 16 + lr;
        for (int j = 0; j < 4; ++j) {
            const int col = n0 + wn + j * 16 + lq * 4;
            if constexpr (sizeof(TC) == 2) {
                bf16x4 ob;
                ob[0] = (__bf16)(acc[i][j][0] + bv4[j].x);
                ob[1] = (__bf16)(acc[i][j][1] + bv4[j].y);
                ob[2] = (__bf16)(acc[i][j][2] + bv4[j].z);
                ob[3] = (__bf16)(acc[i][j][3] + bv4[j].w);
                *(bf16x4*)&C[(size_t)row * ldc + col] = ob;
            } else {
                float4 ov;
                ov.x = acc[i][j][0] + bv4[j].x;
                ov.y = acc[i][j][1] + bv4[j].y;
                ov.z = acc[i][j][2] + bv4[j].z;
                ov.w = acc[i][j][3] + bv4[j].w;
                *(float4*)&C[(size_t)row * ldc + col] = ov;
            }
        }
    }
}

// ---------------- flash attention v7: BM=256, 8 waves x 32 Q rows, 4 waves/SIMD --------------
__global__ __launch_bounds__(512, 4) void attn_kernel(__bf16* __restrict__ qkv)
{
    __shared__ __bf16 Ks[2][64][72];   // [buf][j][d], padded
    __shared__ __bf16 Vt[2][64][72];   // [buf][d][j' packed], padded

    const int tid = threadIdx.x;
    const int wave = tid >> 6, lane = tid & 63;
    const int lr = lane & 15, lq = lane >> 4;

    const int bid = blockIdx.x;          // 512 blocks: 64 bh x 8 qt
    const int xcd = bid & 7, slot = bid >> 3;
    const int bh = xcd * 8 + (slot >> 3);
    const int qt = slot & 7;
    const int b = bh >> 4, h = bh & 15;
    const int rowbase = b * 2048;
    const int q0 = qt * 256;
    const float c1 = 0.125f * LOG2E;

    bf16x8 qf[2][2];
    for (int mt = 0; mt < 2; ++mt)
        for (int ks = 0; ks < 2; ++ks) {
            bf16x8 v = *(const bf16x8*)(qkv +
                (size_t)(rowbase + q0 + wave * 32 + mt * 16 + lr) * 3072 + h * 64 + ks * 32 + lq * 8);
            bf16x8 w;
            for (int e = 0; e < 8; ++e) w[e] = (__bf16)((float)v[e] * c1);
            qf[mt][ks] = w;
        }

    bf16x8 ones8;
    for (int e = 0; e < 8; ++e) ones8[e] = (__bf16)1.0f;

    f32x4 l_acc[2] = {};
    f32x4 o_acc[2][4] = {};

    const int tid2 = tid & 255;
    const int kr = tid2 >> 2, kc = (tid2 & 3) * 16;
    const int g0 = tid2 & 15;
    const int vj0 = g0 * 4, vd0 = (tid2 >> 4) * 4;
    const int vcol = ((g0 >> 3) * 32) + ((g0 & 3) * 8) + (((g0 >> 2) & 1) * 4);
    const __bf16* kbase = qkv + (size_t)(rowbase + kr) * 3072 + 1024 + h * 64 + kc;
    const __bf16* vbase = qkv + (size_t)(rowbase + vj0) * 3072 + 2048 + h * 64 + vd0;

    bf16x8 ka, kb;
    uint2 t0, t1, t2, t3;

    if (wave >= 4) {
        ka = ((const bf16x8*)kbase)[0];
        kb = ((const bf16x8*)kbase)[1];
        *(bf16x8*)&Ks[0][kr][kc] = ka;
        *(bf16x8*)(&Ks[0][kr][kc] + 8) = kb;
    } else {
        t0 = *(const uint2*)(vbase);
        t1 = *(const uint2*)(vbase + 3072);
        t2 = *(const uint2*)(vbase + 6144);
        t3 = *(const uint2*)(vbase + 9216);
        uint2 c0 = { (t0.x & 0xffffu) | (t1.x << 16), (t2.x & 0xffffu) | (t3.x << 16) };
        uint2 d1 = { (t0.x >> 16) | (t1.x & 0xffff0000u), (t2.x >> 16) | (t3.x & 0xffff0000u) };
        uint2 c2 = { (t0.y & 0xffffu) | (t1.y << 16), (t2.y & 0xffffu) | (t3.y << 16) };
        uint2 d3 = { (t0.y >> 16) | (t1.y & 0xffff0000u), (t2.y >> 16) | (t3.y & 0xffff0000u) };
        *(uint2*)&Vt[0][vd0 + 0][vcol] = c0;
        *(uint2*)&Vt[0][vd0 + 1][vcol] = d1;
        *(uint2*)&Vt[0][vd0 + 2][vcol] = c2;
        *(uint2*)&Vt[0][vd0 + 3][vcol] = d3;
    }

    for (int it = 0; it < 32; ++it) {
        const int cur = it & 1;
        __syncthreads();

        if (it + 1 < 32) {
            if (wave >= 4) {
                const __bf16* kg = kbase + (size_t)(it + 1) * 64 * 3072;
                ka = ((const bf16x8*)kg)[0];
                kb = ((const bf16x8*)kg)[1];
            } else {
                const __bf16* vg = vbase + (size_t)(it + 1) * 64 * 3072;
                t0 = *(const uint2*)(vg);
                t1 = *(const uint2*)(vg + 3072);
                t2 = *(const uint2*)(vg + 6144);
                t3 = *(const uint2*)(vg + 9216);
            }
        }

        for (int pi = 0; pi < 2; ++pi) {
            f32x4 s[2][2] = {};
            for (int ks = 0; ks < 2; ++ks) {
                bf16x8 kf0 = *(const bf16x8*)&Ks[cur][(2 * pi + 0) * 16 + lr][ks * 32 + lq * 8];
                bf16x8 kf1 = *(const bf16x8*)&Ks[cur][(2 * pi + 1) * 16 + lr][ks * 32 + lq * 8];
                for (int mt = 0; mt < 2; ++mt) {
                    s[mt][0] = __builtin_amdgcn_mfma_f32_16x16x32_bf16(kf0, qf[mt][ks], s[mt][0], 0, 0, 0);
                    s[mt][1] = __builtin_amdgcn_mfma_f32_16x16x32_bf16(kf1, qf[mt][ks], s[mt][1], 0, 0, 0);
                }
            }
            bf16x8 pfrag[2];
            for (int mt = 0; mt < 2; ++mt) {
                for (int t = 0; t < 2; ++t)
                    for (int r = 0; r < 4; ++r) {
                        float p = __builtin_amdgcn_exp2f(s[mt][t][r]);
                        pfrag[mt][t * 4 + r] = (__bf16)p;
                    }
            }
            for (int mt = 0; mt < 2; ++mt)
                l_acc[mt] = __builtin_amdgcn_mfma_f32_16x16x32_bf16(ones8, pfrag[mt], l_acc[mt], 0, 0, 0);
            for (int dt = 0; dt < 4; ++dt) {
                bf16x8 vf = *(const bf16x8*)&Vt[cur][dt * 16 + lr][pi * 32 + lq * 8];
                for (int mt = 0; mt < 2; ++mt)
                    o_acc[mt][dt] = __builtin_amdgcn_mfma_f32_16x16x32_bf16(vf, pfrag[mt], o_acc[mt][dt], 0, 0, 0);
            }
        }

        if (it + 1 < 32) {
            const int nb = cur ^ 1;
            if (wave >= 4) {
                *(bf16x8*)&Ks[nb][kr][kc] = ka;
                *(bf16x8*)(&Ks[nb][kr][kc] + 8) = kb;
            } else {
                uint2 c0 = { (t0.x & 0xffffu) | (t1.x << 16), (t2.x & 0xffffu) | (t3.x << 16) };
                uint2 d1 = { (t0.x >> 16) | (t1.x & 0xffff0000u), (t2.x >> 16) | (t3.x & 0xffff0000u) };
                uint2 c2 = { (t0.y & 0xffffu) | (t1.y << 16), (t2.y & 0xffffu) | (t3.y << 16) };
                uint2 d3 = { (t0.y >> 16) | (t1.y & 0xffff0000u), (t2.y >> 16) | (t3.y & 0xffff0000u) };
                *(uint2*)&Vt[nb][vd0 + 0][vcol] = c0;
                *(uint2*)&Vt[nb][vd0 + 1][vcol] = d1;
                *(uint2*)&Vt[nb][vd0 + 2][vcol] = c2;
                *(uint2*)&Vt[nb][vd0 + 3][vcol] = d3;
            }
        }
    }

    for (int mt = 0; mt < 2; ++mt) {
        float inv = 1.f / l_acc[mt][0];
        for (int dt = 0; dt < 4; ++dt) {
            bf16x4 ob;
            for (int r = 0; r < 4; ++r) ob[r] = (__bf16)(o_acc[mt][dt][r] * inv);
            *(bf16x4*)(qkv + (size_t)(rowbase + q0 + wave * 32 + mt * 16 + lr) * 3072 +
                       h * 64 + dt * 16 + lq * 4) = ob;
        }
    }
}

extern "C" void kernel_launch(void* const* d_in, const int* in_sizes, int n_in,
                              void* d_out, int out_size, void* d_ws, size_t ws_size,
                              hipStream_t stream) {
    const float* x     = (const float*)d_in[0];   // [8192, 1024] fp32
    const float* Wqkv  = (const float*)d_in[1];   // [3072, 1024] fp32
    const float* Wproj = (const float*)d_in[2];   // [1024, 1024] fp32
    const float* bproj = (const float*)d_in[3];   // [1024] fp32
    float* out   = (float*)d_out;                 // [8192, 1024] fp32
    __bf16* qkvb = (__bf16*)d_ws;                 // [8192, 3072] bf16

    const size_t QKV_E = (size_t)8192 * 3072;
    const size_t X_E   = (size_t)8192 * 1024;
    const size_t WQ_E  = (size_t)3072 * 1024;
    const size_t WP_E  = (size_t)1024 * 1024;
    const bool fast = ws_size >= (QKV_E + X_E + WQ_E + WP_E) * sizeof(__bf16);

    if (fast) {
        __bf16* xb  = qkvb + QKV_E;
        __bf16* wqb = xb + X_E;
        __bf16* wpb = wqb + WQ_E;
        cvt3_f32_bf16<<<dim3(6144), 256, 0, stream>>>(x, xb, Wqkv, wqb, Wproj, wpb);
        gemm_bk64<__bf16><<<dim3(24, 64), 256, 0, stream>>>(
            xb, wqb, nullptr, qkvb, 8192, 3072, 1024, 1024, 1024, 3072);
        attn_kernel<<<dim3(512), 512, 0, stream>>>(qkvb);
        gemm_bk64<float><<<dim3(8, 64), 256, 0, stream>>>(
            qkvb, wpb, bproj, out, 8192, 1024, 1024, 3072, 1024, 1024);
    } else {
        gemm_bt<float, float, __bf16><<<dim3(24, 64), 256, 0, stream>>>(
            x, Wqkv, nullptr, qkvb, 8192, 3072, 1024, 1024, 1024, 3072);
        attn_kernel<<<dim3(512), 512, 0, stream>>>(qkvb);
        gemm_bt<__bf16, float, float><<<dim3(8, 64), 256, 0, stream>>>(
            qkvb, Wproj, bproj, out, 8192, 1024, 1024, 3072, 1024, 1024);
    }
}

// Round 13
// 255.900 us; speedup vs baseline: 1.0871x; 1.0284x over previous
//
#include <hip/hip_runtime.h>
#include <hip/hip_bf16.h>
#include <stdint.h>

typedef __bf16 bf16x4 __attribute__((ext_vector_type(4)));
typedef __bf16 bf16x8 __attribute__((ext_vector_type(8)));
typedef float  f32x4  __attribute__((ext_vector_type(4)));

#define LOG2E 1.44269504088896f

__device__ __forceinline__ void gl2lds16(const __bf16* g, __bf16* l) {
    __builtin_amdgcn_global_load_lds(
        (const __attribute__((address_space(1))) void*)g,
        (__attribute__((address_space(3))) void*)l, 16, 0, 0);
}

// ---------------- fused fp32 -> bf16 for all three tensors (one launch) ----------------------
__global__ __launch_bounds__(256) void cvt3_f32_bf16(
    const float* __restrict__ x,  __bf16* __restrict__ xb,
    const float* __restrict__ wq, __bf16* __restrict__ wqb,
    const float* __restrict__ wp, __bf16* __restrict__ wpb) {
    const int bid = blockIdx.x;
    const float* in; __bf16* out; int base;
    if (bid < 4096)      { in = x;  out = xb;  base = bid; }
    else if (bid < 5632) { in = wq; out = wqb; base = bid - 4096; }
    else                 { in = wp; out = wpb; base = bid - 5632; }
    size_t i = ((size_t)base * 256 + threadIdx.x) * 8;
    float4 a = ((const float4*)(in + i))[0];
    float4 b = ((const float4*)(in + i))[1];
    bf16x8 v;
    v[0] = (__bf16)a.x; v[1] = (__bf16)a.y; v[2] = (__bf16)a.z; v[3] = (__bf16)a.w;
    v[4] = (__bf16)b.x; v[5] = (__bf16)b.y; v[6] = (__bf16)b.z; v[7] = (__bf16)b.w;
    *(bf16x8*)(out + i) = v;
}

// ---------------- 128x128 GEMM, BK=64 + verified swizzle + per-XCD m-row grouping ------------
// r11 kernel (best: zero bank conflicts, BK=64) + block remap for L2 locality:
//   d = by*gx+bx; m-tile = d&63 (fastest), n-tile = d>>6.
// XCD = d%8 (mechanism validated by attn's bid&7 grouping): each XCD owns 8 fixed m-tiles
// (A-slice 2MB, stays L2-resident across all n-phases) and streams one 128-col B-tile
// (0.25MB) per phase -> working set ~2.5MB < 4MB L2 for BOTH gemms. This is the corrected
// form of r4's failed swizzle (which put n fastest per XCD -> 6MB B thrashed L2).
// Expected: A-reads become L2 hits -> FETCH drops AND each per-iter vmcnt(0) drain shortens
// from HBM-class (~900cy) to L2-class (~200cy) latency -- the serial K-chain that r11 showed
// binds both gemms. Requires gridDim.y == 64 (M=8192), true for both calls.
// [r12 rerun: prior round was an infra container failure, no perf data; changes audited
//  hang-free (bijective remap, unconditional setprio, no new barriers).]
template<typename TC>
__global__ __launch_bounds__(256) void gemm_bk64(
    const __bf16* __restrict__ A, const __bf16* __restrict__ B,
    const float* __restrict__ bias, TC* __restrict__ C,
    int M, int N, int K, int lda, int ldb, int ldc)
{
    __shared__ __bf16 As[128][64];   // 16 KB
    __shared__ __bf16 Bs[128][64];   // 16 KB
    const int tid = threadIdx.x;
    const int wave = tid >> 6, lane = tid & 63;
    const int lr = lane & 15, lq = lane >> 4;
    const int d  = blockIdx.y * gridDim.x + blockIdx.x;
    const int m0 = (d & 63) * 128;        // m fastest within an XCD's sequence
    const int n0 = (d >> 6) * 128;
    const int wm = (wave >> 1) * 64, wn = (wave & 1) * 64;

    const int cswz  = (lq * 8) ^ ((lr & 7) << 3);
    const int cswz1 = cswz ^ 32;

    const int srow  = lane >> 3;                    // row within 8-row chunk
    const int selem = ((lane & 7) ^ srow) << 3;     // pre-swizzled global col

    f32x4 acc[4][4] = {};

    const __bf16* ag[4]; const __bf16* bg[4];
    int rls[4];
    for (int s = 0; s < 4; ++s) {
        int chunk = wave * 4 + s;                   // 16 chunks x 8 rows = 128
        rls[s] = chunk * 8;
        ag[s] = A + (size_t)(m0 + chunk * 8 + srow) * lda + selem;
        bg[s] = B + (size_t)(n0 + chunk * 8 + srow) * ldb + selem;
    }

    for (int k0 = 0; k0 < K; k0 += 64) {
        __syncthreads();
#pragma unroll
        for (int s = 0; s < 4; ++s) gl2lds16(ag[s] + k0, &As[rls[s]][0]);
#pragma unroll
        for (int s = 0; s < 4; ++s) gl2lds16(bg[s] + k0, &Bs[rls[s]][0]);
        __syncthreads();
#pragma unroll
        for (int ks = 0; ks < 2; ++ks) {
            const int cc = ks ? cswz1 : cswz;
            bf16x8 af[4], bf[4];
#pragma unroll
            for (int i = 0; i < 4; ++i) af[i] = *(const bf16x8*)&As[wm + i * 16 + lr][cc];
#pragma unroll
            for (int j = 0; j < 4; ++j) bf[j] = *(const bf16x8*)&Bs[wn + j * 16 + lr][cc];
            __builtin_amdgcn_s_setprio(1);
#pragma unroll
            for (int i = 0; i < 4; ++i)
#pragma unroll
                for (int j = 0; j < 4; ++j)
                    acc[i][j] = __builtin_amdgcn_mfma_f32_16x16x32_bf16(bf[j], af[i], acc[i][j], 0, 0, 0);
            __builtin_amdgcn_s_setprio(0);
        }
    }

    // epilogue: D row axis (lq,reg) = N (4 consecutive cols), D col axis (lr) = M row
    float4 bv4[4] = {{0.f,0.f,0.f,0.f},{0.f,0.f,0.f,0.f},{0.f,0.f,0.f,0.f},{0.f,0.f,0.f,0.f}};
    if (bias)
        for (int j = 0; j < 4; ++j)
            bv4[j] = *(const float4*)&bias[n0 + wn + j * 16 + lq * 4];
    for (int i = 0; i < 4; ++i) {
        const int row = m0 + wm + i * 16 + lr;
        for (int j = 0; j < 4; ++j) {
            const int col = n0 + wn + j * 16 + lq * 4;
            if constexpr (sizeof(TC) == 2) {
                bf16x4 ob;
                ob[0] = (__bf16)(acc[i][j][0] + bv4[j].x);
                ob[1] = (__bf16)(acc[i][j][1] + bv4[j].y);
                ob[2] = (__bf16)(acc[i][j][2] + bv4[j].z);
                ob[3] = (__bf16)(acc[i][j][3] + bv4[j].w);
                *(bf16x4*)&C[(size_t)row * ldc + col] = ob;
            } else {
                float4 ov;
                ov.x = acc[i][j][0] + bv4[j].x;
                ov.y = acc[i][j][1] + bv4[j].y;
                ov.z = acc[i][j][2] + bv4[j].z;
                ov.w = acc[i][j][3] + bv4[j].w;
                *(float4*)&C[(size_t)row * ldc + col] = ov;
            }
        }
    }
}

// ---------------- fallback GEMM: fp32 ingest, stage16 cvt ------------------------------------
__device__ __forceinline__ void stage16(const float* __restrict__ g, __bf16* l) {
    float4 a = ((const float4*)g)[0];
    float4 b = ((const float4*)g)[1];
    float4 c = ((const float4*)g)[2];
    float4 d = ((const float4*)g)[3];
    bf16x8 lo, hi;
    lo[0] = (__bf16)a.x; lo[1] = (__bf16)a.y; lo[2] = (__bf16)a.z; lo[3] = (__bf16)a.w;
    lo[4] = (__bf16)b.x; lo[5] = (__bf16)b.y; lo[6] = (__bf16)b.z; lo[7] = (__bf16)b.w;
    hi[0] = (__bf16)c.x; hi[1] = (__bf16)c.y; hi[2] = (__bf16)c.z; hi[3] = (__bf16)c.w;
    hi[4] = (__bf16)d.x; hi[5] = (__bf16)d.y; hi[6] = (__bf16)d.z; hi[7] = (__bf16)d.w;
    ((bf16x8*)l)[0] = lo;
    ((bf16x8*)l)[1] = hi;
}
__device__ __forceinline__ void stage16(const __bf16* __restrict__ g, __bf16* l) {
    ((bf16x8*)l)[0] = ((const bf16x8*)g)[0];
    ((bf16x8*)l)[1] = ((const bf16x8*)g)[1];
}

template<typename TA, typename TB, typename TC>
__global__ __launch_bounds__(256) void gemm_bt(
    const TA* __restrict__ A, const TB* __restrict__ B,
    const float* __restrict__ bias, TC* __restrict__ C,
    int M, int N, int K, int lda, int ldb, int ldc)
{
    __shared__ __bf16 As[128][40];
    __shared__ __bf16 Bs[128][40];
    const int tid = threadIdx.x;
    const int wave = tid >> 6, lane = tid & 63;
    const int lr = lane & 15, lq = lane >> 4;
    const int m0 = blockIdx.y * 128, n0 = blockIdx.x * 128;
    const int wm = (wave >> 1) * 64, wn = (wave & 1) * 64;
    const int srow = tid >> 1, scol = (tid & 1) * 16;

    f32x4 acc[4][4] = {};
    const TA* agp = A + (size_t)(m0 + srow) * lda + scol;
    const TB* bgp = B + (size_t)(n0 + srow) * ldb + scol;

    for (int k0 = 0; k0 < K; k0 += 32) {
        __syncthreads();
        stage16(agp + k0, &As[srow][scol]);
        stage16(bgp + k0, &Bs[srow][scol]);
        __syncthreads();
        bf16x8 af[4], bf[4];
        for (int i = 0; i < 4; ++i) af[i] = *(const bf16x8*)&As[wm + i * 16 + lr][lq * 8];
        for (int j = 0; j < 4; ++j) bf[j] = *(const bf16x8*)&Bs[wn + j * 16 + lr][lq * 8];
        for (int i = 0; i < 4; ++i)
            for (int j = 0; j < 4; ++j)
                acc[i][j] = __builtin_amdgcn_mfma_f32_16x16x32_bf16(bf[j], af[i], acc[i][j], 0, 0, 0);
    }

    float4 bv4[4] = {{0.f,0.f,0.f,0.f},{0.f,0.f,0.f,0.f},{0.f,0.f,0.f,0.f},{0.f,0.f,0.f,0.f}};
    if (bias)
        for (int j = 0; j < 4; ++j)
            bv4[j] = *(const float4*)&bias[n0 + wn + j * 16 + lq * 4];
    for (int i = 0; i < 4; ++i) {
        const int row = m0 + wm + i * 16 + lr;
        for (int j = 0; j < 4; ++j) {
            const int col = n0 + wn + j * 16 + lq * 4;
            if constexpr (sizeof(TC) == 2) {
                bf16x4 ob;
                ob[0] = (__bf16)(acc[i][j][0] + bv4[j].x);
                ob[1] = (__bf16)(acc[i][j][1] + bv4[j].y);
                ob[2] = (__bf16)(acc[i][j][2] + bv4[j].z);
                ob[3] = (__bf16)(acc[i][j][3] + bv4[j].w);
                *(bf16x4*)&C[(size_t)row * ldc + col] = ob;
            } else {
                float4 ov;
                ov.x = acc[i][j][0] + bv4[j].x;
                ov.y = acc[i][j][1] + bv4[j].y;
                ov.z = acc[i][j][2] + bv4[j].z;
                ov.w = acc[i][j][3] + bv4[j].w;
                *(float4*)&C[(size_t)row * ldc + col] = ov;
            }
        }
    }
}

// ---------------- flash attention v8: v7 + T5 setprio around MFMA clusters -------------------
// T5 (catalog: attn +4-7%, m191 -- applies to multi-wave independent-phase blocks, which this
// is at 4 waves/SIMD): boost the pure-MFMA clusters (QK^T; l+PV) so the CU scheduler favors
// them over other waves' softmax VALU / staging. Softmax VALU stays at prio 0.
__global__ __launch_bounds__(512, 4) void attn_kernel(__bf16* __restrict__ qkv)
{
    __shared__ __bf16 Ks[2][64][72];   // [buf][j][d], padded
    __shared__ __bf16 Vt[2][64][72];   // [buf][d][j' packed], padded

    const int tid = threadIdx.x;
    const int wave = tid >> 6, lane = tid & 63;
    const int lr = lane & 15, lq = lane >> 4;

    const int bid = blockIdx.x;          // 512 blocks: 64 bh x 8 qt
    const int xcd = bid & 7, slot = bid >> 3;
    const int bh = xcd * 8 + (slot >> 3);
    const int qt = slot & 7;
    const int b = bh >> 4, h = bh & 15;
    const int rowbase = b * 2048;
    const int q0 = qt * 256;
    const float c1 = 0.125f * LOG2E;

    bf16x8 qf[2][2];
    for (int mt = 0; mt < 2; ++mt)
        for (int ks = 0; ks < 2; ++ks) {
            bf16x8 v = *(const bf16x8*)(qkv +
                (size_t)(rowbase + q0 + wave * 32 + mt * 16 + lr) * 3072 + h * 64 + ks * 32 + lq * 8);
            bf16x8 w;
            for (int e = 0; e < 8; ++e) w[e] = (__bf16)((float)v[e] * c1);
            qf[mt][ks] = w;
        }

    bf16x8 ones8;
    for (int e = 0; e < 8; ++e) ones8[e] = (__bf16)1.0f;

    f32x4 l_acc[2] = {};
    f32x4 o_acc[2][4] = {};

    const int tid2 = tid & 255;
    const int kr = tid2 >> 2, kc = (tid2 & 3) * 16;
    const int g0 = tid2 & 15;
    const int vj0 = g0 * 4, vd0 = (tid2 >> 4) * 4;
    const int vcol = ((g0 >> 3) * 32) + ((g0 & 3) * 8) + (((g0 >> 2) & 1) * 4);
    const __bf16* kbase = qkv + (size_t)(rowbase + kr) * 3072 + 1024 + h * 64 + kc;
    const __bf16* vbase = qkv + (size_t)(rowbase + vj0) * 3072 + 2048 + h * 64 + vd0;

    bf16x8 ka, kb;
    uint2 t0, t1, t2, t3;

    if (wave >= 4) {
        ka = ((const bf16x8*)kbase)[0];
        kb = ((const bf16x8*)kbase)[1];
        *(bf16x8*)&Ks[0][kr][kc] = ka;
        *(bf16x8*)(&Ks[0][kr][kc] + 8) = kb;
    } else {
        t0 = *(const uint2*)(vbase);
        t1 = *(const uint2*)(vbase + 3072);
        t2 = *(const uint2*)(vbase + 6144);
        t3 = *(const uint2*)(vbase + 9216);
        uint2 c0 = { (t0.x & 0xffffu) | (t1.x << 16), (t2.x & 0xffffu) | (t3.x << 16) };
        uint2 d1 = { (t0.x >> 16) | (t1.x & 0xffff0000u), (t2.x >> 16) | (t3.x & 0xffff0000u) };
        uint2 c2 = { (t0.y & 0xffffu) | (t1.y << 16), (t2.y & 0xffffu) | (t3.y << 16) };
        uint2 d3 = { (t0.y >> 16) | (t1.y & 0xffff0000u), (t2.y >> 16) | (t3.y & 0xffff0000u) };
        *(uint2*)&Vt[0][vd0 + 0][vcol] = c0;
        *(uint2*)&Vt[0][vd0 + 1][vcol] = d1;
        *(uint2*)&Vt[0][vd0 + 2][vcol] = c2;
        *(uint2*)&Vt[0][vd0 + 3][vcol] = d3;
    }

    for (int it = 0; it < 32; ++it) {
        const int cur = it & 1;
        __syncthreads();

        if (it + 1 < 32) {
            if (wave >= 4) {
                const __bf16* kg = kbase + (size_t)(it + 1) * 64 * 3072;
                ka = ((const bf16x8*)kg)[0];
                kb = ((const bf16x8*)kg)[1];
            } else {
                const __bf16* vg = vbase + (size_t)(it + 1) * 64 * 3072;
                t0 = *(const uint2*)(vg);
                t1 = *(const uint2*)(vg + 3072);
                t2 = *(const uint2*)(vg + 6144);
                t3 = *(const uint2*)(vg + 9216);
            }
        }

        for (int pi = 0; pi < 2; ++pi) {
            f32x4 s[2][2] = {};
            for (int ks = 0; ks < 2; ++ks) {
                bf16x8 kf0 = *(const bf16x8*)&Ks[cur][(2 * pi + 0) * 16 + lr][ks * 32 + lq * 8];
                bf16x8 kf1 = *(const bf16x8*)&Ks[cur][(2 * pi + 1) * 16 + lr][ks * 32 + lq * 8];
                __builtin_amdgcn_s_setprio(1);
                for (int mt = 0; mt < 2; ++mt) {
                    s[mt][0] = __builtin_amdgcn_mfma_f32_16x16x32_bf16(kf0, qf[mt][ks], s[mt][0], 0, 0, 0);
                    s[mt][1] = __builtin_amdgcn_mfma_f32_16x16x32_bf16(kf1, qf[mt][ks], s[mt][1], 0, 0, 0);
                }
                __builtin_amdgcn_s_setprio(0);
            }
            bf16x8 pfrag[2];
            for (int mt = 0; mt < 2; ++mt) {
                for (int t = 0; t < 2; ++t)
                    for (int r = 0; r < 4; ++r) {
                        float p = __builtin_amdgcn_exp2f(s[mt][t][r]);
                        pfrag[mt][t * 4 + r] = (__bf16)p;
                    }
            }
            __builtin_amdgcn_s_setprio(1);
            for (int mt = 0; mt < 2; ++mt)
                l_acc[mt] = __builtin_amdgcn_mfma_f32_16x16x32_bf16(ones8, pfrag[mt], l_acc[mt], 0, 0, 0);
            for (int dt = 0; dt < 4; ++dt) {
                bf16x8 vf = *(const bf16x8*)&Vt[cur][dt * 16 + lr][pi * 32 + lq * 8];
                for (int mt = 0; mt < 2; ++mt)
                    o_acc[mt][dt] = __builtin_amdgcn_mfma_f32_16x16x32_bf16(vf, pfrag[mt], o_acc[mt][dt], 0, 0, 0);
            }
            __builtin_amdgcn_s_setprio(0);
        }

        if (it + 1 < 32) {
            const int nb = cur ^ 1;
            if (wave >= 4) {
                *(bf16x8*)&Ks[nb][kr][kc] = ka;
                *(bf16x8*)(&Ks[nb][kr][kc] + 8) = kb;
            } else {
                uint2 c0 = { (t0.x & 0xffffu) | (t1.x << 16), (t2.x & 0xffffu) | (t3.x << 16) };
                uint2 d1 = { (t0.x >> 16) | (t1.x & 0xffff0000u), (t2.x >> 16) | (t3.x & 0xffff0000u) };
                uint2 c2 = { (t0.y & 0xffffu) | (t1.y << 16), (t2.y & 0xffffu) | (t3.y << 16) };
                uint2 d3 = { (t0.y >> 16) | (t1.y & 0xffff0000u), (t2.y >> 16) | (t3.y & 0xffff0000u) };
                *(uint2*)&Vt[nb][vd0 + 0][vcol] = c0;
                *(uint2*)&Vt[nb][vd0 + 1][vcol] = d1;
                *(uint2*)&Vt[nb][vd0 + 2][vcol] = c2;
                *(uint2*)&Vt[nb][vd0 + 3][vcol] = d3;
            }
        }
    }

    for (int mt = 0; mt < 2; ++mt) {
        float inv = 1.f / l_acc[mt][0];
        for (int dt = 0; dt < 4; ++dt) {
            bf16x4 ob;
            for (int r = 0; r < 4; ++r) ob[r] = (__bf16)(o_acc[mt][dt][r] * inv);
            *(bf16x4*)(qkv + (size_t)(rowbase + q0 + wave * 32 + mt * 16 + lr) * 3072 +
                       h * 64 + dt * 16 + lq * 4) = ob;
        }
    }
}

extern "C" void kernel_launch(void* const* d_in, const int* in_sizes, int n_in,
                              void* d_out, int out_size, void* d_ws, size_t ws_size,
                              hipStream_t stream) {
    const float* x     = (const float*)d_in[0];   // [8192, 1024] fp32
    const float* Wqkv  = (const float*)d_in[1];   // [3072, 1024] fp32
    const float* Wproj = (const float*)d_in[2];   // [1024, 1024] fp32
    const float* bproj = (const float*)d_in[3];   // [1024] fp32
    float* out   = (float*)d_out;                 // [8192, 1024] fp32
    __bf16* qkvb = (__bf16*)d_ws;                 // [8192, 3072] bf16

    const size_t QKV_E = (size_t)8192 * 3072;
    const size_t X_E   = (size_t)8192 * 1024;
    const size_t WQ_E  = (size_t)3072 * 1024;
    const size_t WP_E  = (size_t)1024 * 1024;
    const bool fast = ws_size >= (QKV_E + X_E + WQ_E + WP_E) * sizeof(__bf16);

    if (fast) {
        __bf16* xb  = qkvb + QKV_E;
        __bf16* wqb = xb + X_E;
        __bf16* wpb = wqb + WQ_E;
        cvt3_f32_bf16<<<dim3(6144), 256, 0, stream>>>(x, xb, Wqkv, wqb, Wproj, wpb);
        gemm_bk64<__bf16><<<dim3(24, 64), 256, 0, stream>>>(
            xb, wqb, nullptr, qkvb, 8192, 3072, 1024, 1024, 1024, 3072);
        attn_kernel<<<dim3(512), 512, 0, stream>>>(qkvb);
        gemm_bk64<float><<<dim3(8, 64), 256, 0, stream>>>(
            qkvb, wpb, bproj, out, 8192, 1024, 1024, 3072, 1024, 1024);
    } else {
        gemm_bt<float, float, __bf16><<<dim3(24, 64), 256, 0, stream>>>(
            x, Wqkv, nullptr, qkvb, 8192, 3072, 1024, 1024, 1024, 3072);
        attn_kernel<<<dim3(512), 512, 0, stream>>>(qkvb);
        gemm_bt<__bf16, float, float><<<dim3(8, 64), 256, 0, stream>>>(
            qkvb, Wproj, bproj, out, 8192, 1024, 1024, 3072, 1024, 1024);
    }
}